// Round 5
// baseline (309.113 us; speedup 1.0000x reference)
//
#include <hip/hip_runtime.h>

#define CH 256
#define HH 128
#define WW 128
#define HW (HH * WW)
#define SEGH 16   // rows per vertical segment
#define NSEG 8    // 128 / SEGH

typedef float v2f __attribute__((ext_vector_type(2)));

__device__ __forceinline__ float rdlane(float v, int l) {
    return __int_as_float(__builtin_amdgcn_readlane(__float_as_int(v), l));
}
__device__ __forceinline__ float uni(float v) {
    return __int_as_float(__builtin_amdgcn_readfirstlane(__float_as_int(v)));
}
__device__ __forceinline__ v2f pkfma(v2f a, v2f b, v2f c) {
    return __builtin_elementwise_fma(a, b, c);   // v_pk_fma_f32 on gfx950
}

// One block per (b,c) image. 1024 threads (16 waves). LDS 72 KiB, 2 blocks/CU.
//
// Mix weights m_k are FOLDED into the scan input coefficients c_k (linearity):
// every scan directly produces m_k * scan_k, so all per-element mixes are adds.
//
//   Phase 0: thread (hr,hk): 4 float4 global x loads (the ONLY global x read),
//            params computed under the load latency, then stage to LDS plane
//            at swizzled slots P(hk,j) = (hk^2j)+8j (r3-verified: write b128,
//            column b32 read, both conflict-free). xr[16] STAYS IN REGISTERS.
//   barrier A
//   V1:      thread (col,seg): xv[16] from LDS columns (was L2 global in r3),
//            packed (b2,b3) segment summary chains -> scr.
//   barrier B   (everyone consumed x from the plane -> H may overwrite)
//   Fixup:   Sin/Tin from <=7 scr summaries (wave-uniform trips).
//   H:       packed compose (blo,rB)/(bhi,rA), 3-step KS over 8 lanes,
//            scalar rr backward pass, forward l pass + add -> plane slots
//            (single write per slot, same pattern as r3 -> liveness ~= r3,
//            which measured no spill; r4's reload/RMW variant spilled 160MB).
//   barrier C
//   V2:      r3-style scalar: forward s + plane add into o[16], backward t +
//            coalesced store. (Packed variant needs +16 VGPR; not worth risk.)
__global__ __launch_bounds__(1024, 8) void dscan_kernel(
    const float* __restrict__ x,
    const float* __restrict__ decay_logits,
    const float* __restrict__ mix_logits,
    const float* __restrict__ input_scale,
    float* __restrict__ out)
{
    extern __shared__ float smem[];
    float* __restrict__ xs  = smem;           // 16384 floats: x-plane, then result plane
    float* __restrict__ scr = smem + HW;      // 2048 floats: b2 (1024) + b3 (1024)

    const int img  = blockIdx.x;              // b*256 + c
    const int c    = img & (CH - 1);
    const int tid  = threadIdx.x;
    const int lane = tid & 63;

    const float* __restrict__ xg = x + (size_t)img * HW;
    float* __restrict__ og = out + (size_t)img * HW;

    const int hr = tid >> 3;              // H row 0..127
    const int hk = tid & 7;               // H chunk 0..7
    float* __restrict__ prow = xs + hr * WW;

    // ---- issue the only global x read first; params hide its latency ----
    const float* __restrict__ xrow = xg + hr * WW + hk * 16;
    const float4 a0 = *(const float4*)(xrow + 0);
    const float4 a1 = *(const float4*)(xrow + 4);
    const float4 a2 = *(const float4*)(xrow + 8);
    const float4 a3 = *(const float4*)(xrow + 12);

    // ---- lane-split per-channel params ----
    float pv = 0.0f;
    {
        const int j = lane & 3;
        const int g = lane >> 2;
        if (g == 0) {
            const float v = decay_logits[j * CH + c];
            pv = fminf(fmaxf(1.0f / (1.0f + expf(-v)), 0.05f), 0.995f);
        } else if (g == 1) {
            const float b0 = mix_logits[0 * CH + c];
            const float b1 = mix_logits[1 * CH + c];
            const float b2 = mix_logits[2 * CH + c];
            const float b3 = mix_logits[3 * CH + c];
            const float mm = fmaxf(fmaxf(b0, b1), fmaxf(b2, b3));
            const float bj = (j == 0) ? b0 : (j == 1) ? b1 : (j == 2) ? b2 : b3;
            pv = expf(bj - mm);
        } else if (g == 2) {
            pv = 1.0f + tanhf(input_scale[j * CH + c]);
        }
    }
    const float d0 = rdlane(pv, 0), d1 = rdlane(pv, 1);
    const float d2 = rdlane(pv, 2), d3 = rdlane(pv, 3);
    const float e0 = rdlane(pv, 4), e1 = rdlane(pv, 5);
    const float e2 = rdlane(pv, 6), e3 = rdlane(pv, 7);
    const float s0 = rdlane(pv, 8), s1 = rdlane(pv, 9);
    const float s2 = rdlane(pv, 10), s3 = rdlane(pv, 11);

    const float einv = uni(1.0f / (e0 + e1 + e2 + e3));
    // mix weights folded into scan coefficients (scans are linear)
    const float c0 = uni((1.0f - d0) * s0 * (e0 * einv));
    const float c1 = uni((1.0f - d1) * s1 * (e1 * einv));
    const float c2 = uni((1.0f - d2) * s2 * (e2 * einv));
    const float c3 = uni((1.0f - d3) * s3 * (e3 * einv));

    // powers: p8 = d^8 (compose join), q[k] = d^(16*2^k) (KS steps)
    float p8_0, p8_1, q0[3], q1[3];
    {
        float a = d0 * d0; a = a * a;             // d0^4
        p8_0 = uni(a * a);                        // d0^8
        q0[0] = uni(p8_0 * p8_0); q0[1] = uni(q0[0] * q0[0]); q0[2] = uni(q0[1] * q0[1]);
        float b = d1 * d1; b = b * b;
        p8_1 = uni(b * b);
        q1[0] = uni(p8_1 * p8_1); q1[1] = uni(q1[0] * q1[0]); q1[2] = uni(q1[1] * q1[1]);
    }
    float t2v = d2 * d2; t2v = t2v * t2v; t2v = t2v * t2v; const float d2p16 = uni(t2v * t2v);
    float t3v = d3 * d3; t3v = t3v * t3v; t3v = t3v * t3v; const float d3p16 = uni(t3v * t3v);

    // ---- stage x into the plane (swizzled slots); keep xr in registers ----
    *(float4*)(prow + 4 * ((hk ^ 0) +  0)) = a0;
    *(float4*)(prow + 4 * ((hk ^ 2) +  8)) = a1;
    *(float4*)(prow + 4 * ((hk ^ 4) + 16)) = a2;
    *(float4*)(prow + 4 * ((hk ^ 6) + 24)) = a3;

    float xr[16];
    xr[0]=a0.x;  xr[1]=a0.y;  xr[2]=a0.z;  xr[3]=a0.w;
    xr[4]=a1.x;  xr[5]=a1.y;  xr[6]=a1.z;  xr[7]=a1.w;
    xr[8]=a2.x;  xr[9]=a2.y;  xr[10]=a2.z; xr[11]=a2.w;
    xr[12]=a3.x; xr[13]=a3.y; xr[14]=a3.z; xr[15]=a3.w;

    __syncthreads();   // A: x-plane complete

    // ---- V1: column reads from LDS, packed segment summaries ----
    const int col = tid & (WW - 1);       // 0..127
    const int seg = tid >> 7;             // 0..7
    const int coff = 4 * (((col >> 4) ^ (2 * ((col >> 2) & 3))) + 8 * ((col >> 2) & 3))
                   + (col & 3);
    float xv[SEGH];                       // x column chunk, lives to the end
    {
        const float* __restrict__ pcol = xs + seg * SEGH * WW + coff;
#pragma unroll
        for (int i = 0; i < SEGH; ++i) xv[i] = pcol[i * WW];

        // packed (b2 fwd | b3 bwd-Horner) chain
        const v2f dd23 = {d2, d3};
        v2f b23 = {c2 * xv[0], xv[15]};
#pragma unroll
        for (int i = 1; i < SEGH; ++i) {
            const v2f in = {c2 * xv[i], xv[15 - i]};
            b23 = pkfma(dd23, b23, in);
        }
        scr[tid]        = b23.x;          // m2-scaled forward exit state
        scr[1024 + tid] = b23.y * c3;     // m3-scaled reverse exit state
    }

    __syncthreads();   // B: plane reads done -> H may overwrite; scr ready

    // ---- Fixup: incoming vertical states; wave-uniform trip counts ----
    float Sin = 0.0f;
    for (int j = 0; j < seg; ++j)
        Sin = fmaf(d2p16, Sin, scr[j * WW + col]);
    float Tin = 0.0f;
    for (int j = NSEG - 1; j > seg; --j)
        Tin = fmaf(d3p16, Tin, scr[1024 + j * WW + col]);

    // ---- H: row scans, plane overwrite (single write/slot, r3 pattern) ----
    {
        // packed compose: pA=(blo fwd 0..7 | rB bwd 7..0), pB=(bhi fwd 8..15 | rA bwd 15..8)
        const v2f dd01 = {d0, d1};
        v2f pA = {c0 * xr[0], c1 * xr[7]};
        v2f pB = {c0 * xr[8], c1 * xr[15]};
#pragma unroll
        for (int i = 1; i < 8; ++i) {
            const v2f ia = {c0 * xr[i],     c1 * xr[7 - i]};
            const v2f ib = {c0 * xr[8 + i], c1 * xr[15 - i]};
            pA = pkfma(dd01, pA, ia);
            pB = pkfma(dd01, pB, ib);
        }
        float bL = fmaf(p8_0, pA.x, pB.x);
        float bR = fmaf(p8_1, pB.y, pA.y);

        // constant-decay Kogge-Stone over the 8 chunks of this row
#pragma unroll
        for (int kk = 0; kk < 3; ++kk) {
            const int off = 1 << kk;
            const float bU = __shfl_up(bL, (unsigned)off, 8);
            bL = fmaf(q0[kk], (hk >= off) ? bU : 0.0f, bL);
            const float bD = __shfl_down(bR, (unsigned)off, 8);
            bR = fmaf(q1[kk], (hk < 8 - off) ? bD : 0.0f, bR);
        }
        float EL = __shfl_up(bL, 1u, 8);
        if (hk == 0) EL = 0.0f;
        float ER = __shfl_down(bR, 1u, 8);
        if (hk == 7) ER = 0.0f;

        // backward rr pass, then forward l pass + add (folded mix) + store
        float rr[16];
        float t = ER;
#pragma unroll
        for (int i = 15; i >= 0; --i) { t = fmaf(d1, t, c1 * xr[i]); rr[i] = t; }

        float l = EL;
#pragma unroll
        for (int j = 0; j < 4; ++j) {
            float4 o4;
            l = fmaf(d0, l, c0 * xr[4*j + 0]); o4.x = l + rr[4*j + 0];
            l = fmaf(d0, l, c0 * xr[4*j + 1]); o4.y = l + rr[4*j + 1];
            l = fmaf(d0, l, c0 * xr[4*j + 2]); o4.z = l + rr[4*j + 2];
            l = fmaf(d0, l, c0 * xr[4*j + 3]); o4.w = l + rr[4*j + 3];
            *(float4*)(prow + 4 * ((hk ^ (2*j)) + 8*j)) = o4;
        }
    }

    __syncthreads();   // C: result plane complete

    // ---- V2: forward s + plane add; backward t + coalesced store ----
    {
        const int rbase = seg * SEGH;
        const float* __restrict__ pcol = xs + rbase * WW + coff;

        float o[SEGH];
        float s = Sin;
#pragma unroll
        for (int i = 0; i < SEGH; ++i) {
            s = fmaf(d2, s, c2 * xv[i]);      // s = m2 * tb_i
            o[i] = s + pcol[i * WW];
        }
        float t = Tin;
        float* __restrict__ ocol = og + rbase * WW + col;
#pragma unroll
        for (int i = SEGH - 1; i >= 0; --i) {
            t = fmaf(d3, t, c3 * xv[i]);      // t = m3 * bt_i
            ocol[i * WW] = t + o[i];
        }
    }
}

extern "C" void kernel_launch(void* const* d_in, const int* in_sizes, int n_in,
                              void* d_out, int out_size, void* d_ws, size_t ws_size,
                              hipStream_t stream) {
    const float* x  = (const float*)d_in[0];
    const float* dl = (const float*)d_in[1];
    const float* ml = (const float*)d_in[2];
    const float* is = (const float*)d_in[3];
    float* out = (float*)d_out;

    const size_t lds_bytes = (size_t)(HW + 2048) * sizeof(float);   // 73728

    static bool attr_set = false;   // idempotent host-side attribute; value never changes
    if (!attr_set) {
        (void)hipFuncSetAttribute((const void*)dscan_kernel,
                                  hipFuncAttributeMaxDynamicSharedMemorySize,
                                  (int)lds_bytes);
        attr_set = true;
    }

    dim3 grid(2048), block(1024);
    hipLaunchKernelGGL(dscan_kernel, grid, block, lds_bytes, stream, x, dl, ml, is, out);
}